// Round 9
// baseline (339.181 us; speedup 1.0000x reference)
//
#include <hip/hip_runtime.h>
#include <stdint.h>

typedef unsigned short u16;
typedef short s16x8 __attribute__((ext_vector_type(8)));
typedef float f32x4 __attribute__((ext_vector_type(4)));

#define SQ 2048
#define DH 64
#define BN 64
#define STR 72             // prep-only LDS transpose stride (shorts)
#define SPECIAL_START 2040
#define NBH 32             // b*h
#define NKV 8              // b*hk
#define NQP 16             // qp (128-row) index 0..15
#define NCLS 40            // slice classes per bh (<=8 ktiles each)
#define NITEMS_F (NCLS * 32)   // 1280 sliced items
#define ATTN_GRID_F 768        // 3 blocks/CU
// softclamp+softmax folded to exp2: p = 2^( t*poly(t*t) - KEF ), t = s * K1F
#define K1F  0.18033688011112043f    // 0.125 * log2(e)
#define KPAF 4.9244826e-9f           // (2/15)*k^2, k = (0.02/log2e)^2
#define KPBF -6.406040185576019e-5f  // -k/3
#define KEF  36.067376022224085f     // 25 * log2(e)  (constant softmax shift = 25)

union U8 { s16x8 v; short e[8]; };
union F4 { f32x4 v; float e[4]; };

// class: qp | kt0<<4 | nk<<9 | nsl<<13  (heavy-first; verified R7/R8)
#define CL(qp,k0,nk,ns) ((unsigned short)((qp) | ((k0) << 4) | ((nk) << 9) | ((ns) << 13)))
__device__ const unsigned short ETAB[NCLS] = {
    CL(15,0,8,4), CL(15,8,8,4), CL(15,16,8,4), CL(15,24,8,4),
    CL(14,0,8,4), CL(14,8,8,4), CL(14,16,8,4), CL(14,24,8,4),
    CL(13,0,8,4), CL(13,8,8,4), CL(13,16,8,4),
    CL(12,0,8,4), CL(12,8,8,4), CL(12,16,8,4),
    CL(11,0,8,3), CL(11,8,8,3), CL(11,16,8,3),
    CL(10,0,8,3), CL(10,8,8,3), CL(10,16,8,3),
    CL(9,0,8,3),  CL(9,8,8,3),
    CL(8,0,8,3),  CL(8,8,8,3),
    CL(7,0,8,2),  CL(7,8,8,2),
    CL(6,0,8,2),  CL(6,8,8,2),
    CL(5,0,8,2),
    CL(4,0,8,2),
    CL(3,0,8,1),
    CL(2,0,8,1),
    CL(13,24,4,4), CL(12,24,4,4), CL(9,16,4,3), CL(8,16,4,3),
    CL(5,8,4,2),   CL(4,8,4,2),   CL(1,0,4,1),  CL(0,0,4,1)
};
// per-qp class-id lists (pad -1) — used by the fused last-finisher combine
__device__ const signed char QPS[16][4] = {
    {39,-1,-1,-1}, {38,-1,-1,-1}, {31,-1,-1,-1}, {30,-1,-1,-1},
    {29,37,-1,-1}, {28,36,-1,-1}, {26,27,-1,-1}, {24,25,-1,-1},
    {22,23,35,-1}, {20,21,34,-1}, {17,18,19,-1}, {14,15,16,-1},
    {11,12,13,33}, {8,9,10,32},   {4,5,6,7},     {0,1,2,3}
};

__device__ __forceinline__ u16 f2bf(float x) {  // round-to-nearest-even
    uint32_t u = __float_as_uint(x);
    return (u16)((u + 0x7fffu + ((u >> 16) & 1u)) >> 16);
}
__device__ __forceinline__ uint32_t pkbf(float a, float b) {  // pack 2 bf16, 1 instr
    uint32_t r;
    asm("v_cvt_pk_bf16_f32 %0, %1, %2" : "=v"(r) : "v"(a), "v"(b));
    return r;
}
__device__ __forceinline__ float exp2hw(float x) {
    float r; asm("v_exp_f32 %0, %1" : "=v"(r) : "v"(x)); return r;
}
__device__ __forceinline__ float2 fsincos(float ang) {  // {sin, cos}, fast HW path
    float r = ang * 0.15915494309189535f;   // radians -> revolutions
    r -= floorf(r);
    float s, c;
    asm("v_sin_f32 %0, %1" : "=v"(s) : "v"(r));
    asm("v_cos_f32 %0, %1" : "=v"(c) : "v"(r));
    return make_float2(s, c);
}
// async global->LDS, 16B per lane; LDS dest = wave-uniform base + lane*16
__device__ __forceinline__ void gl_lds16(const void* g, void* l) {
    __builtin_amdgcn_global_load_lds(
        (const __attribute__((address_space(1))) uint32_t*)g,
        (__attribute__((address_space(3))) uint32_t*)l, 16, 0, 0);
}

// ---- prep: V tiles (transpose to [tile][d][kv]) + K rope rows (bf16) ----
#define VTILES (NKV * 32)                 // 256 tile-blocks
#define RK (NKV * SQ)                     // 16384 K rows
#define KBLK (RK / 32)                    // 512 row-blocks
__global__ __launch_bounds__(256)
void prep_kernel(const float* __restrict__ kg, const float* __restrict__ vg,
                 const float* __restrict__ rotg,
                 u16* __restrict__ kp, u16* __restrict__ vp,
                 uint32_t* __restrict__ cnt, uint32_t* __restrict__ done)
{
    const int tid = threadIdx.x;
    if (blockIdx.x == 0) {                 // reset queue + combine counters
        if (tid == 0) *cnt = 0u;
        done[tid] = 0u;
        done[tid + 256] = 0u;
    }
    if (blockIdx.x < VTILES) {
        __shared__ short Vls[64 * STR];
        const int tile = blockIdx.x;                   // bkv*32 + kt
        const float* src = vg + ((size_t)(tile >> 5) * SQ + (size_t)(tile & 31) * 64) * DH;
        {
            int kv = tid >> 2, c0 = (tid & 3) * 16;
            const float* s4 = src + (size_t)kv * DH + c0;
            float4 f0 = *(const float4*)(s4);
            float4 f1 = *(const float4*)(s4 + 4);
            float4 f2 = *(const float4*)(s4 + 8);
            float4 f3 = *(const float4*)(s4 + 12);
            uint4 w0 = make_uint4(pkbf(f0.x, f0.y), pkbf(f0.z, f0.w),
                                  pkbf(f1.x, f1.y), pkbf(f1.z, f1.w));
            uint4 w1 = make_uint4(pkbf(f2.x, f2.y), pkbf(f2.z, f2.w),
                                  pkbf(f3.x, f3.y), pkbf(f3.z, f3.w));
            *(uint4*)&Vls[kv * STR + c0]     = w0;
            *(uint4*)&Vls[kv * STR + c0 + 8] = w1;
        }
        __syncthreads();
        {
            int d = tid >> 2, c0 = (tid & 3) * 16;
            U8 o0, o1;
#pragma unroll
            for (int j = 0; j < 16; j++)
                (j < 8 ? o0 : o1).e[j & 7] = Vls[(c0 + j) * STR + d];  // transpose
            u16* dst = vp + (((size_t)tile * 64 + d) << 6) + c0;
            *(s16x8*)dst       = o0.v;
            *(s16x8*)(dst + 8) = o1.v;
        }
    } else {
        int bx = blockIdx.x - VTILES;
        int r8 = tid >> 3, c0 = (tid & 7) * 4;      // c0 in 0..28 (<32)
        int r = bx * 32 + r8;                        // r in [0, RK)
        const int s = r & (SQ - 1);
        const float* src = kg + (size_t)r * DH;
        u16*         dst = kp + (size_t)r * DH;
        float4 a  = *(const float4*)(src + c0);
        float4 b  = *(const float4*)(src + c0 + 32);
        float4 rv = *(const float4*)(rotg + (size_t)s * DH + c0);
        float2 s0 = fsincos(rv.x), s1 = fsincos(rv.y),
               s2 = fsincos(rv.z), s3 = fsincos(rv.w);
        float lo0 = a.x * s0.y - b.x * s0.x, hi0 = b.x * s0.y + a.x * s0.x;
        float lo1 = a.y * s1.y - b.y * s1.x, hi1 = b.y * s1.y + a.y * s1.x;
        float lo2 = a.z * s2.y - b.z * s2.x, hi2 = b.z * s2.y + a.z * s2.x;
        float lo3 = a.w * s3.y - b.w * s3.x, hi3 = b.w * s3.y + a.w * s3.x;
        *(uint2*)(dst + c0)      = make_uint2(pkbf(lo0, lo1), pkbf(lo2, lo3));
        *(uint2*)(dst + c0 + 32) = make_uint2(pkbf(hi0, hi1), pkbf(hi2, hi3));
    }
}

// ---- attn: R7 body (K AND V through gl_lds LDS dbuf — the proven 56us
// structure) + fused last-finisher combine (no separate reduce kernel).
__global__ __launch_bounds__(256)
__attribute__((amdgpu_waves_per_eu(3, 4)))
void attn_fast(const float* __restrict__ qg, const float* __restrict__ rotg,
               const u16* __restrict__ kp, const u16* __restrict__ vp,
               uint32_t* __restrict__ cnt, uint32_t* __restrict__ done,
               float* __restrict__ pacc, float* __restrict__ lacc,
               float* __restrict__ outg)
{
    const int tid = threadIdx.x;
    const int wv = tid >> 6, lane = tid & 63;
    const int l15 = lane & 15, quad = lane >> 4;
    const int swl = (l15 & 7) << 3;            // fragment-row swizzle (shorts)

    __shared__ __align__(16) u16 Ks[2][4096];  // 16 KB K dbuf
    __shared__ __align__(16) u16 Vt[2][4096];  // 16 KB V dbuf
    __shared__ __align__(16) short Ps[128 * 64]; // 16 KB wave-private P
    __shared__ int s_w, s_d;

    // staging geometry (rule 21): linear LDS dest + inverse-swizzled source
    const int gcol = (((lane & 7) ^ (lane >> 3)) << 3);
    const int goff0 = ((wv * 16 + (lane >> 3)) << 6) + gcol;
    const int goff1 = goff0 + (8 << 6);
    const int lds0 = (wv * 2) * 512;           // wave-uniform
    const int lds1 = lds0 + 512;

    short* prow0 = &Ps[(wv * 32 + l15) * 64];
    short* prow1 = &Ps[(wv * 32 + 16 + l15) * 64];

    for (;;) {
        __syncthreads();                       // protect s_w/s_d + LDS reuse
        if (tid == 0) s_w = (int)atomicAdd(cnt, 1u);
        __syncthreads();
        const int w = s_w;
        if (w >= NITEMS_F) break;
        const int g = w >> 5;                  // class (heavy-first)
        const int u = w & 31, bkv = u >> 2;    // consecutive pops share bkv
        const int bh = ((bkv >> 2) << 4) | ((bkv & 3) << 2) | (u & 3);
        const int e = ETAB[g];
        const int qp  = e & 15;
        const int kt0 = (e >> 4) & 31;
        const int nk  = (e >> 9) & 15;         // 4 or 8
        const int nsl = e >> 13;               // slices for this qp
        const int qrow0 = qp * 128 + wv * 32;

        const u16* kbase = kp + (size_t)bkv * (SQ * DH);
        const u16* vbase = vp + (size_t)bkv * (SQ * DH);
        auto stage = [&](int kt, int cb) {
            const u16* tk = kbase + ((size_t)kt << 12);
            const u16* tv = vbase + ((size_t)kt << 12);
            gl_lds16(tk + goff0, &Ks[cb][lds0]);
            gl_lds16(tk + goff1, &Ks[cb][lds1]);
            gl_lds16(tv + goff0, &Vt[cb][lds0]);
            gl_lds16(tv + goff1, &Vt[cb][lds1]);
        };
        stage(kt0, 0);   // first-tile DMA flies under the Q rope below

        // ---- Q rope -> registers ----
        s16x8 qf[2][2];
#pragma unroll
        for (int nq = 0; nq < 2; nq++) {
            const int srow = qrow0 + nq * 16 + l15;
            const float* gq = qg + ((size_t)bh * SQ + srow) * DH + quad * 8;
            float a[8], b[8];
            *(float4*)&a[0] = *(const float4*)(gq);
            *(float4*)&a[4] = *(const float4*)(gq + 4);
            *(float4*)&b[0] = *(const float4*)(gq + 32);
            *(float4*)&b[4] = *(const float4*)(gq + 36);
            const float* rrow = rotg + (size_t)srow * DH + quad * 8;
            float lo[8], hi[8];
#pragma unroll
            for (int j = 0; j < 8; j++) {
                float2 sc = fsincos(rrow[j]);
                lo[j] = a[j] * sc.y - b[j] * sc.x;
                hi[j] = b[j] * sc.y + a[j] * sc.x;
            }
            U8 q0, q1;
#pragma unroll
            for (int j = 0; j < 4; j++) {
                ((uint32_t*)&q0.v)[j] = pkbf(lo[2 * j], lo[2 * j + 1]);
                ((uint32_t*)&q1.v)[j] = pkbf(hi[2 * j], hi[2 * j + 1]);
            }
            qf[nq][0] = q0.v;
            qf[nq][1] = q1.v;
        }

        F4 oa[2][4];
#pragma unroll
        for (int nq = 0; nq < 2; nq++)
#pragma unroll
            for (int mb = 0; mb < 4; mb++) oa[nq][mb].v = (f32x4){0.f, 0.f, 0.f, 0.f};
        F4 lsa0, lsa1;
        lsa0.v = (f32x4){0.f, 0.f, 0.f, 0.f};
        lsa1.v = (f32x4){0.f, 0.f, 0.f, 0.f};

        __syncthreads();   // first tile staged (drains vmcnt)
        int cb = 0;

        for (int i = 0; i < nk; i++) {
            const int kt = kt0 + i;
            if (i + 1 < nk) stage(kt + 1, cb ^ 1);  // full phase before drain

            // ---- QK^T: S^T[kv][q]; each kf feeds both q-tiles ----
            F4 sa[2][4];
            __builtin_amdgcn_s_setprio(1);
#pragma unroll
            for (int ks = 0; ks < 2; ks++)
#pragma unroll
                for (int mb = 0; mb < 4; mb++) {
                    s16x8 kf = *(const s16x8*)&Ks[cb][(mb * 16 + l15) * 64 + ((ks * 32 + quad * 8) ^ swl)];
                    sa[0][mb].v = __builtin_amdgcn_mfma_f32_16x16x32_bf16(
                        kf, qf[0][ks], ks ? sa[0][mb].v : (f32x4){0.f, 0.f, 0.f, 0.f}, 0, 0, 0);
                    sa[1][mb].v = __builtin_amdgcn_mfma_f32_16x16x32_bf16(
                        kf, qf[1][ks], ks ? sa[1][mb].v : (f32x4){0.f, 0.f, 0.f, 0.f}, 0, 0, 0);
                }
            __builtin_amdgcn_s_setprio(0);

            // ---- softclamp + constant-shift softmax (exp2-folded, vectorized) ----
            const int last = (kt == 31);
#pragma unroll
            for (int nq = 0; nq < 2; nq++) {
                const int qglob = qrow0 + nq * 16 + l15;
                short* prow = nq ? prow1 : prow0;
#pragma unroll
                for (int mb = 0; mb < 4; mb++) {
                    F4 t, w2, py, pa;
                    t.v  = sa[nq][mb].v * K1F;
                    w2.v = t.v * t.v;
                    py.v = w2.v * KPAF + KPBF;
                    py.v = w2.v * py.v + 1.0f;
                    t.v  = t.v * py.v - KEF;
                    pa.e[0] = exp2hw(t.e[0]);
                    pa.e[1] = exp2hw(t.e[1]);
                    pa.e[2] = exp2hw(t.e[2]);
                    pa.e[3] = exp2hw(t.e[3]);
                    if (last && qglob < SPECIAL_START) {   // special-token mask
#pragma unroll
                        for (int c = 0; c < 4; c++) {
                            int kvglob = kt * BN + mb * 16 + quad * 4 + c;
                            if (kvglob >= SPECIAL_START) pa.e[c] = 0.f;
                        }
                    }
                    if (nq) lsa1.v = lsa1.v + pa.v; else lsa0.v = lsa0.v + pa.v;
                    uint2 pw = make_uint2(pkbf(pa.e[0], pa.e[1]),
                                          pkbf(pa.e[2], pa.e[3]));
                    *(uint2*)&prow[(mb * 16 + quad * 4) ^ swl] = pw;  // wave-private
                }
            }

            // ---- PV: O^T[d][q] += Vt.P; each vf feeds both q-tiles ----
            s16x8 pf00 = *(const s16x8*)&prow0[(quad * 8) ^ swl];
            s16x8 pf01 = *(const s16x8*)&prow0[(32 + quad * 8) ^ swl];
            s16x8 pf10 = *(const s16x8*)&prow1[(quad * 8) ^ swl];
            s16x8 pf11 = *(const s16x8*)&prow1[(32 + quad * 8) ^ swl];
            __builtin_amdgcn_s_setprio(1);
#pragma unroll
            for (int mb = 0; mb < 4; mb++) {
                s16x8 vf = *(const s16x8*)&Vt[cb][(mb * 16 + l15) * 64 + ((quad * 8) ^ swl)];
                oa[0][mb].v = __builtin_amdgcn_mfma_f32_16x16x32_bf16(vf, pf00, oa[0][mb].v, 0, 0, 0);
                oa[1][mb].v = __builtin_amdgcn_mfma_f32_16x16x32_bf16(vf, pf10, oa[1][mb].v, 0, 0, 0);
            }
#pragma unroll
            for (int mb = 0; mb < 4; mb++) {
                s16x8 vf = *(const s16x8*)&Vt[cb][(mb * 16 + l15) * 64 + ((32 + quad * 8) ^ swl)];
                oa[0][mb].v = __builtin_amdgcn_mfma_f32_16x16x32_bf16(vf, pf01, oa[0][mb].v, 0, 0, 0);
                oa[1][mb].v = __builtin_amdgcn_mfma_f32_16x16x32_bf16(vf, pf11, oa[1][mb].v, 0, 0, 0);
            }
            __builtin_amdgcn_s_setprio(0);

            __syncthreads();   // buf[cb] reads done; kt+1 DMA landed
            cb ^= 1;
        }

        // ---- row lsums across quads (kv partitioned by quad) ----
        float lsum0 = (lsa0.e[0] + lsa0.e[1]) + (lsa0.e[2] + lsa0.e[3]);
        float lsum1 = (lsa1.e[0] + lsa1.e[1]) + (lsa1.e[2] + lsa1.e[3]);
        lsum0 += __shfl_xor(lsum0, 16, 64);
        lsum0 += __shfl_xor(lsum0, 32, 64);
        lsum1 += __shfl_xor(lsum1, 16, 64);
        lsum1 += __shfl_xor(lsum1, 32, 64);

        if (nsl == 1) {
            // ---- single-slice qp: write out directly ----
#pragma unroll
            for (int nq = 0; nq < 2; nq++) {
                const float rl = 1.0f / (nq ? lsum1 : lsum0);
                const int qrow = qrow0 + nq * 16 + l15;
                float* orow = outg + ((size_t)bh * SQ + qrow) * DH;
#pragma unroll
                for (int mb = 0; mb < 4; mb++) {
                    const int d0 = mb * 16 + quad * 4;
                    const F4& o = oa[nq][mb];
                    *(float4*)(orow + d0) = make_float4(o.e[0] * rl, o.e[1] * rl,
                                                        o.e[2] * rl, o.e[3] * rl);
                }
            }
        } else {
            // ---- store raw partials; last finisher combines (proven R8) ----
            float* pitem = pacc + (size_t)w * 8192;
            float* litem = lacc + (size_t)w * 128;
#pragma unroll
            for (int nq = 0; nq < 2; nq++) {
                const int row = wv * 32 + nq * 16 + l15;
#pragma unroll
                for (int mb = 0; mb < 4; mb++) {
                    const F4& o = oa[nq][mb];
                    *(float4*)&pitem[row * 64 + mb * 16 + quad * 4] =
                        make_float4(o.e[0], o.e[1], o.e[2], o.e[3]);
                }
                if (quad == 0) litem[row] = nq ? lsum1 : lsum0;
            }
            __threadfence();               // release partials (device scope)
            __syncthreads();
            if (tid == 0) s_d = (int)atomicAdd(&done[bh * 16 + qp], 1u);
            __syncthreads();
            if (s_d == nsl - 1) {          // we are the last slice: combine
                __threadfence();           // acquire siblings' partials
#pragma unroll
                for (int s = 0; s < 4; s++) {
                    const int g2 = QPS[qp][s];
                    if (g2 < 0 || g2 == g) continue;
                    const size_t id = (size_t)g2 * 32 + u;
                    const float* pp = pacc + id * 8192;
                    const float* lp = lacc + id * 128;
#pragma unroll
                    for (int nq = 0; nq < 2; nq++) {
                        const int row = wv * 32 + nq * 16 + l15;
#pragma unroll
                        for (int mb = 0; mb < 4; mb++) {
                            float4 v = *(const float4*)&pp[row * 64 + mb * 16 + quad * 4];
                            F4& o = oa[nq][mb];
                            o.e[0] += v.x; o.e[1] += v.y; o.e[2] += v.z; o.e[3] += v.w;
                        }
                        if (nq) lsum1 += lp[row]; else lsum0 += lp[row];
                    }
                }
#pragma unroll
                for (int nq = 0; nq < 2; nq++) {
                    const float rl = 1.0f / (nq ? lsum1 : lsum0);
                    const int qrow = qrow0 + nq * 16 + l15;
                    float* orow = outg + ((size_t)bh * SQ + qrow) * DH;
#pragma unroll
                    for (int mb = 0; mb < 4; mb++) {
                        const int d0 = mb * 16 + quad * 4;
                        const F4& o = oa[nq][mb];
                        *(float4*)(orow + d0) = make_float4(o.e[0] * rl, o.e[1] * rl,
                                                            o.e[2] * rl, o.e[3] * rl);
                    }
                }
            }
        }
    }
}

// ---- fallback (no workspace): self-contained, K/V staged through LDS ----
__global__ __launch_bounds__(256, 4)
void attn_fallback(const float* __restrict__ qg, const float* __restrict__ kg,
                   const float* __restrict__ vg, const float* __restrict__ rotg,
                   float* __restrict__ outg)
{
    const int x  = blockIdx.x;
    const int qt = (x & 1) ? (31 - (x >> 1)) : (x >> 1);
    const int bh = blockIdx.y;
    const int bb = bh >> 4, hh = bh & 15;
    const int bkv = bb * 4 + (hh >> 2);
    const int qs = qt * 64;

    const int tid = threadIdx.x;
    const int wv = tid >> 6, lane = tid & 63;
    const int l15 = lane & 15, quad = lane >> 4;
    const int swl = (l15 & 7) << 3;

    __shared__ __align__(16) short QPs[64 * 64];
    __shared__ __align__(16) short Ks[2][BN * 64];
    __shared__ __align__(16) short Vt[2][DH * 64];

    const size_t kvbase = ((size_t)bkv * SQ) * DH;
    const int nkt = (qt / 4 + 1) * 4;
    const int qglob = qs + wv * 16 + l15;

    {
        int rr = tid >> 2, c0 = (tid & 3) * 8;
        int srow = qs + rr;
        const float* gq = qg + ((size_t)bh * SQ + srow) * DH;
        float a[8], b[8];
        *(float4*)&a[0] = *(const float4*)(gq + c0);
        *(float4*)&a[4] = *(const float4*)(gq + c0 + 4);
        *(float4*)&b[0] = *(const float4*)(gq + c0 + 32);
        *(float4*)&b[4] = *(const float4*)(gq + c0 + 36);
        U8 o0, o1;
#pragma unroll
        for (int j = 0; j < 8; j++) {
            float2 sc = fsincos(rotg[(size_t)srow * DH + c0 + j]);
            o0.e[j] = (short)f2bf(a[j] * sc.y - b[j] * sc.x);
            o1.e[j] = (short)f2bf(b[j] * sc.y + a[j] * sc.x);
        }
        int sw2 = (rr & 7) << 3;
        *(s16x8*)&QPs[rr * 64 + (c0 ^ sw2)]        = o0.v;
        *(s16x8*)&QPs[rr * 64 + ((c0 + 32) ^ sw2)] = o1.v;
    }
    __syncthreads();

    s16x8 qf[2];
#pragma unroll
    for (int ks = 0; ks < 2; ks++)
        qf[ks] = *(const s16x8*)&QPs[(wv * 16 + l15) * 64 + ((ks * 32 + quad * 8) ^ swl)];

    F4 oa[4];
#pragma unroll
    for (int mb = 0; mb < 4; mb++) oa[mb].v = (f32x4){0.f, 0.f, 0.f, 0.f};
    float lsum = 0.f;

    for (int kt = 0; kt < nkt; kt++) {
        const int cb = kt & 1;
        {
            int rr = tid >> 2, c0 = (tid & 3) * 8;
            int srow = kt * BN + rr;
            const float* gk = kg + kvbase + (size_t)srow * DH;
            float a[8], b[8];
            *(float4*)&a[0] = *(const float4*)(gk + c0);
            *(float4*)&a[4] = *(const float4*)(gk + c0 + 4);
            *(float4*)&b[0] = *(const float4*)(gk + c0 + 32);
            *(float4*)&b[4] = *(const float4*)(gk + c0 + 36);
            U8 o0, o1;
#pragma unroll
            for (int j = 0; j < 8; j++) {
                float2 sc = fsincos(rotg[(size_t)(srow & (SQ - 1)) * DH + c0 + j]);
                o0.e[j] = (short)f2bf(a[j] * sc.y - b[j] * sc.x);
                o1.e[j] = (short)f2bf(b[j] * sc.y + a[j] * sc.x);
            }
            int sw2 = (rr & 7) << 3;
            *(s16x8*)&Ks[cb][rr * 64 + (c0 ^ sw2)]        = o0.v;
            *(s16x8*)&Ks[cb][rr * 64 + ((c0 + 32) ^ sw2)] = o1.v;
        }
        {
            int rr = tid >> 2, c0 = (tid & 3) * 16;
            const float* gv = vg + kvbase + (size_t)(kt * BN + rr) * DH;
            float vv[16];
#pragma unroll
            for (int t = 0; t < 4; t++)
                *(float4*)&vv[t * 4] = *(const float4*)(gv + c0 + t * 4);
#pragma unroll
            for (int j = 0; j < 16; j++) {
                int d = c0 + j;
                Vt[cb][d * 64 + (rr ^ ((d & 7) << 3))] = (short)f2bf(vv[j]);
            }
        }
        __syncthreads();

        F4 sa[4];
#pragma unroll
        for (int mb = 0; mb < 4; mb++) sa[mb].v = (f32x4){0.f, 0.f, 0.f, 0.f};
#pragma unroll
        for (int ks = 0; ks < 2; ks++)
#pragma unroll
            for (int mb = 0; mb < 4; mb++) {
                s16x8 kf = *(const s16x8*)&Ks[cb][(mb * 16 + l15) * 64 + ((ks * 32 + quad * 8) ^ swl)];
                sa[mb].v = __builtin_amdgcn_mfma_f32_16x16x32_bf16(kf, qf[ks], sa[mb].v, 0, 0, 0);
            }

        F4 pa[4];
#pragma unroll
        for (int mb = 0; mb < 4; mb++)
#pragma unroll
            for (int c = 0; c < 4; c++) {
                float t  = sa[mb].e[c] * K1F;
                float w2 = t * t;
                float poly = fmaf(w2, fmaf(w2, KPAF, KPBF), 1.0f);
                pa[mb].e[c] = exp2hw(fmaf(t, poly, -KEF));
            }
        if (kt == 31 && qglob < SPECIAL_START) {
#pragma unroll
            for (int mb = 0; mb < 4; mb++)
#pragma unroll
                for (int c = 0; c < 4; c++) {
                    int kvglob = kt * BN + mb * 16 + quad * 4 + c;
                    if (kvglob >= SPECIAL_START) pa[mb].e[c] = 0.f;
                }
        }
        short* prow = &QPs[(wv * 16 + l15) * 64];
#pragma unroll
        for (int mb = 0; mb < 4; mb++) {
            lsum += (pa[mb].e[0] + pa[mb].e[1]) + (pa[mb].e[2] + pa[mb].e[3]);
            uint2 pw = make_uint2(pkbf(pa[mb].e[0], pa[mb].e[1]),
                                  pkbf(pa[mb].e[2], pa[mb].e[3]));
            *(uint2*)&prow[(mb * 16 + quad * 4) ^ swl] = pw;
        }
#pragma unroll
        for (int ks = 0; ks < 2; ks++) {
            s16x8 pf = *(const s16x8*)&prow[(ks * 32 + quad * 8) ^ swl];
#pragma unroll
            for (int mb = 0; mb < 4; mb++) {
                s16x8 vf = *(const s16x8*)&Vt[cb][(mb * 16 + l15) * 64 + ((ks * 32 + quad * 8) ^ swl)];
                oa[mb].v = __builtin_amdgcn_mfma_f32_16x16x32_bf16(vf, pf, oa[mb].v, 0, 0, 0);
            }
        }
        __syncthreads();
    }

    lsum += __shfl_xor(lsum, 16, 64);
    lsum += __shfl_xor(lsum, 32, 64);

    float rl = 1.0f / lsum;
    int qrow = qs + wv * 16 + l15;
    float* orow = outg + ((size_t)bh * SQ + qrow) * DH;
#pragma unroll
    for (int mb = 0; mb < 4; mb++) {
        int d0 = mb * 16 + quad * 4;
        *(float4*)(orow + d0) = make_float4(oa[mb].e[0] * rl, oa[mb].e[1] * rl,
                                            oa[mb].e[2] * rl, oa[mb].e[3] * rl);
    }
}

extern "C" void kernel_launch(void* const* d_in, const int* in_sizes, int n_in,
                              void* d_out, int out_size, void* d_ws, size_t ws_size,
                              hipStream_t stream) {
    const float* q   = (const float*)d_in[0];
    const float* k   = (const float*)d_in[1];
    const float* v   = (const float*)d_in[2];
    const float* rot = (const float*)d_in[3];
    float* out = (float*)d_out;

    char* w = (char*)d_ws;
    const size_t k_bytes = (size_t)NKV * SQ * DH * sizeof(u16);     // 2 MiB
    const size_t v_bytes = k_bytes;                                 // 2 MiB
    size_t off = k_bytes + v_bytes;
    uint32_t* cnt  = (uint32_t*)(w + off); off += 256;
    uint32_t* done = (uint32_t*)(w + off); off += 4096;             // 512 counters
    float* pacc = (float*)(w + off); off += (size_t)NITEMS_F * 8192 * sizeof(float);
    float* lacc = (float*)(w + off); off += (size_t)NITEMS_F * 128 * sizeof(float);
    const size_t full_need = off;                                   // ~47 MB

    u16* kp = (u16*)w;
    u16* vp = (u16*)(w + k_bytes);

    if (ws_size >= full_need) {
        hipLaunchKernelGGL(prep_kernel, dim3(VTILES + KBLK), dim3(256), 0, stream,
                           k, v, rot, kp, vp, cnt, done);
        hipLaunchKernelGGL(attn_fast, dim3(ATTN_GRID_F), dim3(256), 0, stream,
                           q, rot, kp, vp, cnt, done, pacc, lacc, out);
    } else {
        hipLaunchKernelGGL(attn_fallback, dim3(32, NBH), dim3(256), 0, stream,
                           q, k, v, rot, out);
    }
}

// Round 10
// 131.557 us; speedup vs baseline: 2.5782x; 2.5782x over previous
//
#include <hip/hip_runtime.h>
#include <stdint.h>

typedef unsigned short u16;
typedef short s16x8 __attribute__((ext_vector_type(8)));
typedef float f32x4 __attribute__((ext_vector_type(4)));

#define SQ 2048
#define DH 64
#define BN 64
#define STR 72             // prep-only LDS transpose stride (shorts)
#define SPECIAL_START 2040
#define NBH 32             // b*h
#define NKV 8              // b*hk
#define NQP 16             // qp (128-row) index 0..15
#define NCLS 40            // slice classes per bh (<=8 ktiles each)
#define NITEMS_F (NCLS * 32)   // 1280 sliced items
#define ATTN_GRID_F 768        // 3 blocks/CU
#define NMQP 12                // multi-slice qps (4..15)
#define RED_GRID (NBH * NMQP * 4)  // 1536 blocks, 32 rows each
// softclamp+softmax folded to exp2: p = 2^( t*poly(t*t) - KEF ), t = s * K1F
#define K1F  0.18033688011112043f    // 0.125 * log2(e)
#define KPAF 4.9244826e-9f           // (2/15)*k^2, k = (0.02/log2e)^2
#define KPBF -6.406040185576019e-5f  // -k/3
#define KEF  36.067376022224085f     // 25 * log2(e)  (constant softmax shift = 25)

union U8 { s16x8 v; short e[8]; };
union F4 { f32x4 v; float e[4]; };

// class: qp | kt0<<4 | nk<<9 | nsl<<13  (heavy-first; measured R7 = 56us attn)
#define CL(qp,k0,nk,ns) ((unsigned short)((qp) | ((k0) << 4) | ((nk) << 9) | ((ns) << 13)))
__device__ const unsigned short ETAB[NCLS] = {
    CL(15,0,8,4), CL(15,8,8,4), CL(15,16,8,4), CL(15,24,8,4),
    CL(14,0,8,4), CL(14,8,8,4), CL(14,16,8,4), CL(14,24,8,4),
    CL(13,0,8,4), CL(13,8,8,4), CL(13,16,8,4),
    CL(12,0,8,4), CL(12,8,8,4), CL(12,16,8,4),
    CL(11,0,8,3), CL(11,8,8,3), CL(11,16,8,3),
    CL(10,0,8,3), CL(10,8,8,3), CL(10,16,8,3),
    CL(9,0,8,3),  CL(9,8,8,3),
    CL(8,0,8,3),  CL(8,8,8,3),
    CL(7,0,8,2),  CL(7,8,8,2),
    CL(6,0,8,2),  CL(6,8,8,2),
    CL(5,0,8,2),
    CL(4,0,8,2),
    CL(3,0,8,1),
    CL(2,0,8,1),
    CL(13,24,4,4), CL(12,24,4,4), CL(9,16,4,3), CL(8,16,4,3),
    CL(5,8,4,2),   CL(4,8,4,2),   CL(1,0,4,1),  CL(0,0,4,1)
};
// per-qp class-id lists (pad -1) — consumed by reduce_kernel
__device__ const signed char QPS[16][4] = {
    {39,-1,-1,-1}, {38,-1,-1,-1}, {31,-1,-1,-1}, {30,-1,-1,-1},
    {29,37,-1,-1}, {28,36,-1,-1}, {26,27,-1,-1}, {24,25,-1,-1},
    {22,23,35,-1}, {20,21,34,-1}, {17,18,19,-1}, {14,15,16,-1},
    {11,12,13,33}, {8,9,10,32},   {4,5,6,7},     {0,1,2,3}
};

__device__ __forceinline__ u16 f2bf(float x) {  // round-to-nearest-even
    uint32_t u = __float_as_uint(x);
    return (u16)((u + 0x7fffu + ((u >> 16) & 1u)) >> 16);
}
__device__ __forceinline__ uint32_t pkbf(float a, float b) {  // pack 2 bf16, 1 instr
    uint32_t r;
    asm("v_cvt_pk_bf16_f32 %0, %1, %2" : "=v"(r) : "v"(a), "v"(b));
    return r;
}
__device__ __forceinline__ float exp2hw(float x) {
    float r; asm("v_exp_f32 %0, %1" : "=v"(r) : "v"(x)); return r;
}
__device__ __forceinline__ float2 fsincos(float ang) {  // {sin, cos}, fast HW path
    float r = ang * 0.15915494309189535f;   // radians -> revolutions
    r -= floorf(r);
    float s, c;
    asm("v_sin_f32 %0, %1" : "=v"(s) : "v"(r));
    asm("v_cos_f32 %0, %1" : "=v"(c) : "v"(r));
    return make_float2(s, c);
}
// async global->LDS, 16B per lane; LDS dest = wave-uniform base + lane*16
__device__ __forceinline__ void gl_lds16(const void* g, void* l) {
    __builtin_amdgcn_global_load_lds(
        (const __attribute__((address_space(1))) uint32_t*)g,
        (__attribute__((address_space(3))) uint32_t*)l, 16, 0, 0);
}

// ---- prep: V tiles (transpose to [tile][d][kv]) + K rope rows (bf16) ----
#define VTILES (NKV * 32)                 // 256 tile-blocks
#define RK (NKV * SQ)                     // 16384 K rows
#define KBLK (RK / 32)                    // 512 row-blocks
__global__ __launch_bounds__(256)
void prep_kernel(const float* __restrict__ kg, const float* __restrict__ vg,
                 const float* __restrict__ rotg,
                 u16* __restrict__ kp, u16* __restrict__ vp,
                 uint32_t* __restrict__ cnt)
{
    const int tid = threadIdx.x;
    if (blockIdx.x == 0 && tid == 0) *cnt = 0u;
    if (blockIdx.x < VTILES) {
        __shared__ short Vls[64 * STR];
        const int tile = blockIdx.x;                   // bkv*32 + kt
        const float* src = vg + ((size_t)(tile >> 5) * SQ + (size_t)(tile & 31) * 64) * DH;
        {
            int kv = tid >> 2, c0 = (tid & 3) * 16;
            const float* s4 = src + (size_t)kv * DH + c0;
            float4 f0 = *(const float4*)(s4);
            float4 f1 = *(const float4*)(s4 + 4);
            float4 f2 = *(const float4*)(s4 + 8);
            float4 f3 = *(const float4*)(s4 + 12);
            uint4 w0 = make_uint4(pkbf(f0.x, f0.y), pkbf(f0.z, f0.w),
                                  pkbf(f1.x, f1.y), pkbf(f1.z, f1.w));
            uint4 w1 = make_uint4(pkbf(f2.x, f2.y), pkbf(f2.z, f2.w),
                                  pkbf(f3.x, f3.y), pkbf(f3.z, f3.w));
            *(uint4*)&Vls[kv * STR + c0]     = w0;
            *(uint4*)&Vls[kv * STR + c0 + 8] = w1;
        }
        __syncthreads();
        {
            int d = tid >> 2, c0 = (tid & 3) * 16;
            U8 o0, o1;
#pragma unroll
            for (int j = 0; j < 16; j++)
                (j < 8 ? o0 : o1).e[j & 7] = Vls[(c0 + j) * STR + d];  // transpose
            u16* dst = vp + (((size_t)tile * 64 + d) << 6) + c0;
            *(s16x8*)dst       = o0.v;
            *(s16x8*)(dst + 8) = o1.v;
        }
    } else {
        int bx = blockIdx.x - VTILES;
        int r8 = tid >> 3, c0 = (tid & 7) * 4;      // c0 in 0..28 (<32)
        int r = bx * 32 + r8;                        // r in [0, RK)
        const int s = r & (SQ - 1);
        const float* src = kg + (size_t)r * DH;
        u16*         dst = kp + (size_t)r * DH;
        float4 a  = *(const float4*)(src + c0);
        float4 b  = *(const float4*)(src + c0 + 32);
        float4 rv = *(const float4*)(rotg + (size_t)s * DH + c0);
        float2 s0 = fsincos(rv.x), s1 = fsincos(rv.y),
               s2 = fsincos(rv.z), s3 = fsincos(rv.w);
        float lo0 = a.x * s0.y - b.x * s0.x, hi0 = b.x * s0.y + a.x * s0.x;
        float lo1 = a.y * s1.y - b.y * s1.x, hi1 = b.y * s1.y + a.y * s1.x;
        float lo2 = a.z * s2.y - b.z * s2.x, hi2 = b.z * s2.y + a.z * s2.x;
        float lo3 = a.w * s3.y - b.w * s3.x, hi3 = b.w * s3.y + a.w * s3.x;
        *(uint2*)(dst + c0)      = make_uint2(pkbf(lo0, lo1), pkbf(lo2, lo3));
        *(uint2*)(dst + c0 + 32) = make_uint2(pkbf(hi0, hi1), pkbf(hi2, hi3));
    }
}

// ---- attn: EXACT R7 body (measured 56us) + fence-free nsl==1 direct write.
// NO device fences anywhere (R8/R9 lesson: __threadfence = L2 flush poison).
__global__ __launch_bounds__(256)
__attribute__((amdgpu_waves_per_eu(3, 4)))
void attn_fast(const float* __restrict__ qg, const float* __restrict__ rotg,
               const u16* __restrict__ kp, const u16* __restrict__ vp,
               uint32_t* __restrict__ cnt,
               float* __restrict__ pacc, float* __restrict__ lacc,
               float* __restrict__ outg)
{
    const int tid = threadIdx.x;
    const int wv = tid >> 6, lane = tid & 63;
    const int l15 = lane & 15, quad = lane >> 4;
    const int swl = (l15 & 7) << 3;            // fragment-row swizzle (shorts)

    __shared__ __align__(16) u16 Ks[2][4096];  // 16 KB K dbuf
    __shared__ __align__(16) u16 Vt[2][4096];  // 16 KB V dbuf
    __shared__ __align__(16) short Ps[128 * 64]; // 16 KB wave-private P
    __shared__ int s_w;

    // staging geometry (rule 21): linear LDS dest + inverse-swizzled source
    const int gcol = (((lane & 7) ^ (lane >> 3)) << 3);
    const int goff0 = ((wv * 16 + (lane >> 3)) << 6) + gcol;
    const int goff1 = goff0 + (8 << 6);
    const int lds0 = (wv * 2) * 512;           // wave-uniform
    const int lds1 = lds0 + 512;

    short* prow0 = &Ps[(wv * 32 + l15) * 64];
    short* prow1 = &Ps[(wv * 32 + 16 + l15) * 64];

    for (;;) {
        __syncthreads();                       // protect s_w + LDS reuse
        if (tid == 0) s_w = (int)atomicAdd(cnt, 1u);
        __syncthreads();
        const int w = s_w;
        if (w >= NITEMS_F) break;
        const int g = w >> 5;                  // class (heavy-first)
        const int u = w & 31, bkv = u >> 2;    // consecutive pops share bkv
        const int bh = ((bkv >> 2) << 4) | ((bkv & 3) << 2) | (u & 3);
        const int e = ETAB[g];
        const int qp  = e & 15;
        const int kt0 = (e >> 4) & 31;
        const int nk  = (e >> 9) & 15;         // 4 or 8
        const int nsl = e >> 13;               // slices for this qp
        const int qrow0 = qp * 128 + wv * 32;

        const u16* kbase = kp + (size_t)bkv * (SQ * DH);
        const u16* vbase = vp + (size_t)bkv * (SQ * DH);
        auto stage = [&](int kt, int cb) {
            const u16* tk = kbase + ((size_t)kt << 12);
            const u16* tv = vbase + ((size_t)kt << 12);
            gl_lds16(tk + goff0, &Ks[cb][lds0]);
            gl_lds16(tk + goff1, &Ks[cb][lds1]);
            gl_lds16(tv + goff0, &Vt[cb][lds0]);
            gl_lds16(tv + goff1, &Vt[cb][lds1]);
        };
        stage(kt0, 0);   // first-tile DMA flies under the Q rope below

        // ---- Q rope -> registers ----
        s16x8 qf[2][2];
#pragma unroll
        for (int nq = 0; nq < 2; nq++) {
            const int srow = qrow0 + nq * 16 + l15;
            const float* gq = qg + ((size_t)bh * SQ + srow) * DH + quad * 8;
            float a[8], b[8];
            *(float4*)&a[0] = *(const float4*)(gq);
            *(float4*)&a[4] = *(const float4*)(gq + 4);
            *(float4*)&b[0] = *(const float4*)(gq + 32);
            *(float4*)&b[4] = *(const float4*)(gq + 36);
            const float* rrow = rotg + (size_t)srow * DH + quad * 8;
            float lo[8], hi[8];
#pragma unroll
            for (int j = 0; j < 8; j++) {
                float2 sc = fsincos(rrow[j]);
                lo[j] = a[j] * sc.y - b[j] * sc.x;
                hi[j] = b[j] * sc.y + a[j] * sc.x;
            }
            U8 q0, q1;
#pragma unroll
            for (int j = 0; j < 4; j++) {
                ((uint32_t*)&q0.v)[j] = pkbf(lo[2 * j], lo[2 * j + 1]);
                ((uint32_t*)&q1.v)[j] = pkbf(hi[2 * j], hi[2 * j + 1]);
            }
            qf[nq][0] = q0.v;
            qf[nq][1] = q1.v;
        }

        F4 oa[2][4];
#pragma unroll
        for (int nq = 0; nq < 2; nq++)
#pragma unroll
            for (int mb = 0; mb < 4; mb++) oa[nq][mb].v = (f32x4){0.f, 0.f, 0.f, 0.f};
        F4 lsa0, lsa1;
        lsa0.v = (f32x4){0.f, 0.f, 0.f, 0.f};
        lsa1.v = (f32x4){0.f, 0.f, 0.f, 0.f};

        __syncthreads();   // first tile staged (drains vmcnt)
        int cb = 0;

        for (int i = 0; i < nk; i++) {
            const int kt = kt0 + i;
            if (i + 1 < nk) stage(kt + 1, cb ^ 1);  // full phase before drain

            // ---- QK^T: S^T[kv][q]; each kf feeds both q-tiles ----
            F4 sa[2][4];
            __builtin_amdgcn_s_setprio(1);
#pragma unroll
            for (int ks = 0; ks < 2; ks++)
#pragma unroll
                for (int mb = 0; mb < 4; mb++) {
                    s16x8 kf = *(const s16x8*)&Ks[cb][(mb * 16 + l15) * 64 + ((ks * 32 + quad * 8) ^ swl)];
                    sa[0][mb].v = __builtin_amdgcn_mfma_f32_16x16x32_bf16(
                        kf, qf[0][ks], ks ? sa[0][mb].v : (f32x4){0.f, 0.f, 0.f, 0.f}, 0, 0, 0);
                    sa[1][mb].v = __builtin_amdgcn_mfma_f32_16x16x32_bf16(
                        kf, qf[1][ks], ks ? sa[1][mb].v : (f32x4){0.f, 0.f, 0.f, 0.f}, 0, 0, 0);
                }
            __builtin_amdgcn_s_setprio(0);

            // ---- softclamp + constant-shift softmax (exp2-folded, vectorized) ----
            const int last = (kt == 31);
#pragma unroll
            for (int nq = 0; nq < 2; nq++) {
                const int qglob = qrow0 + nq * 16 + l15;
                short* prow = nq ? prow1 : prow0;
#pragma unroll
                for (int mb = 0; mb < 4; mb++) {
                    F4 t, w2, py, pa;
                    t.v  = sa[nq][mb].v * K1F;
                    w2.v = t.v * t.v;
                    py.v = w2.v * KPAF + KPBF;
                    py.v = w2.v * py.v + 1.0f;
                    t.v  = t.v * py.v - KEF;
                    pa.e[0] = exp2hw(t.e[0]);
                    pa.e[1] = exp2hw(t.e[1]);
                    pa.e[2] = exp2hw(t.e[2]);
                    pa.e[3] = exp2hw(t.e[3]);
                    if (last && qglob < SPECIAL_START) {   // special-token mask
#pragma unroll
                        for (int c = 0; c < 4; c++) {
                            int kvglob = kt * BN + mb * 16 + quad * 4 + c;
                            if (kvglob >= SPECIAL_START) pa.e[c] = 0.f;
                        }
                    }
                    if (nq) lsa1.v = lsa1.v + pa.v; else lsa0.v = lsa0.v + pa.v;
                    uint2 pw = make_uint2(pkbf(pa.e[0], pa.e[1]),
                                          pkbf(pa.e[2], pa.e[3]));
                    *(uint2*)&prow[(mb * 16 + quad * 4) ^ swl] = pw;  // wave-private
                }
            }

            // ---- PV: O^T[d][q] += Vt.P; each vf feeds both q-tiles ----
            s16x8 pf00 = *(const s16x8*)&prow0[(quad * 8) ^ swl];
            s16x8 pf01 = *(const s16x8*)&prow0[(32 + quad * 8) ^ swl];
            s16x8 pf10 = *(const s16x8*)&prow1[(quad * 8) ^ swl];
            s16x8 pf11 = *(const s16x8*)&prow1[(32 + quad * 8) ^ swl];
            __builtin_amdgcn_s_setprio(1);
#pragma unroll
            for (int mb = 0; mb < 4; mb++) {
                s16x8 vf = *(const s16x8*)&Vt[cb][(mb * 16 + l15) * 64 + ((quad * 8) ^ swl)];
                oa[0][mb].v = __builtin_amdgcn_mfma_f32_16x16x32_bf16(vf, pf00, oa[0][mb].v, 0, 0, 0);
                oa[1][mb].v = __builtin_amdgcn_mfma_f32_16x16x32_bf16(vf, pf10, oa[1][mb].v, 0, 0, 0);
            }
#pragma unroll
            for (int mb = 0; mb < 4; mb++) {
                s16x8 vf = *(const s16x8*)&Vt[cb][(mb * 16 + l15) * 64 + ((32 + quad * 8) ^ swl)];
                oa[0][mb].v = __builtin_amdgcn_mfma_f32_16x16x32_bf16(vf, pf01, oa[0][mb].v, 0, 0, 0);
                oa[1][mb].v = __builtin_amdgcn_mfma_f32_16x16x32_bf16(vf, pf11, oa[1][mb].v, 0, 0, 0);
            }
            __builtin_amdgcn_s_setprio(0);

            __syncthreads();   // buf[cb] reads done; kt+1 DMA landed
            cb ^= 1;
        }

        // ---- row lsums across quads (kv partitioned by quad) ----
        float lsum0 = (lsa0.e[0] + lsa0.e[1]) + (lsa0.e[2] + lsa0.e[3]);
        float lsum1 = (lsa1.e[0] + lsa1.e[1]) + (lsa1.e[2] + lsa1.e[3]);
        lsum0 += __shfl_xor(lsum0, 16, 64);
        lsum0 += __shfl_xor(lsum0, 32, 64);
        lsum1 += __shfl_xor(lsum1, 16, 64);
        lsum1 += __shfl_xor(lsum1, 32, 64);

        if (nsl == 1) {
            // ---- single-slice qp: direct write (fence-free, plain stores) ----
#pragma unroll
            for (int nq = 0; nq < 2; nq++) {
                const float rl = 1.0f / (nq ? lsum1 : lsum0);
                const int qrow = qrow0 + nq * 16 + l15;
                float* orow = outg + ((size_t)bh * SQ + qrow) * DH;
#pragma unroll
                for (int mb = 0; mb < 4; mb++) {
                    const int d0 = mb * 16 + quad * 4;
                    const F4& o = oa[nq][mb];
                    *(float4*)(orow + d0) = make_float4(o.e[0] * rl, o.e[1] * rl,
                                                        o.e[2] * rl, o.e[3] * rl);
                }
            }
        } else {
            // ---- store raw partials (plain stores; reduce kernel combines) ----
            float* pitem = pacc + (size_t)w * 8192;
            float* litem = lacc + (size_t)w * 128;
#pragma unroll
            for (int nq = 0; nq < 2; nq++) {
                const int row = wv * 32 + nq * 16 + l15;
#pragma unroll
                for (int mb = 0; mb < 4; mb++) {
                    const F4& o = oa[nq][mb];
                    *(float4*)&pitem[row * 64 + mb * 16 + quad * 4] =
                        make_float4(o.e[0], o.e[1], o.e[2], o.e[3]);
                }
                if (quad == 0) litem[row] = nq ? lsum1 : lsum0;
            }
        }
    }
}

// ---- reduce: only multi-slice qps (4..15); 1536 blocks x 32 rows for BW ----
__global__ __launch_bounds__(256)
void reduce_kernel(const float* __restrict__ pacc, const float* __restrict__ lacc,
                   float* __restrict__ outg)
{
    const int blk = blockIdx.x;            // pair*4 + rowgroup
    const int pair = blk >> 2, rgrp = blk & 3;
    const int qp = 4 + (pair % NMQP);
    const int bh = pair / NMQP;
    const int t = threadIdx.x;
    const int row = rgrp * 32 + (t >> 3);  // 0..127
    const int c0 = (t & 7) * 8;            // 0..56
    // inverse bh -> u mapping (matches attn's pop decode)
    const int bkv = (bh >> 4) * 4 + ((bh >> 2) & 3);
    const int u = (bkv << 2) | (bh & 3);

    float acc[8];
#pragma unroll
    for (int j = 0; j < 8; j++) acc[j] = 0.f;
    float ls = 0.f;
#pragma unroll
    for (int s = 0; s < 4; s++) {
        const int g = QPS[qp][s];
        if (g < 0) break;
        const size_t id = (size_t)g * 32 + u;
        const float* p = pacc + id * 8192 + row * 64 + c0;
        float4 v0 = ((const float4*)p)[0];
        float4 v1 = ((const float4*)p)[1];
        acc[0] += v0.x; acc[1] += v0.y; acc[2] += v0.z; acc[3] += v0.w;
        acc[4] += v1.x; acc[5] += v1.y; acc[6] += v1.z; acc[7] += v1.w;
        ls += lacc[id * 128 + row];
    }
    const float rl = 1.0f / ls;
    float* orow = outg + ((size_t)bh * SQ + qp * 128 + row) * DH + c0;
    ((float4*)orow)[0] = make_float4(acc[0] * rl, acc[1] * rl, acc[2] * rl, acc[3] * rl);
    ((float4*)orow)[1] = make_float4(acc[4] * rl, acc[5] * rl, acc[6] * rl, acc[7] * rl);
}

// ---- fallback (no workspace): self-contained, K/V staged through LDS ----
__global__ __launch_bounds__(256, 4)
void attn_fallback(const float* __restrict__ qg, const float* __restrict__ kg,
                   const float* __restrict__ vg, const float* __restrict__ rotg,
                   float* __restrict__ outg)
{
    const int x  = blockIdx.x;
    const int qt = (x & 1) ? (31 - (x >> 1)) : (x >> 1);
    const int bh = blockIdx.y;
    const int bb = bh >> 4, hh = bh & 15;
    const int bkv = bb * 4 + (hh >> 2);
    const int qs = qt * 64;

    const int tid = threadIdx.x;
    const int wv = tid >> 6, lane = tid & 63;
    const int l15 = lane & 15, quad = lane >> 4;
    const int swl = (l15 & 7) << 3;

    __shared__ __align__(16) short QPs[64 * 64];
    __shared__ __align__(16) short Ks[2][BN * 64];
    __shared__ __align__(16) short Vt[2][DH * 64];

    const size_t kvbase = ((size_t)bkv * SQ) * DH;
    const int nkt = (qt / 4 + 1) * 4;
    const int qglob = qs + wv * 16 + l15;

    {
        int rr = tid >> 2, c0 = (tid & 3) * 8;
        int srow = qs + rr;
        const float* gq = qg + ((size_t)bh * SQ + srow) * DH;
        float a[8], b[8];
        *(float4*)&a[0] = *(const float4*)(gq + c0);
        *(float4*)&a[4] = *(const float4*)(gq + c0 + 4);
        *(float4*)&b[0] = *(const float4*)(gq + c0 + 32);
        *(float4*)&b[4] = *(const float4*)(gq + c0 + 36);
        U8 o0, o1;
#pragma unroll
        for (int j = 0; j < 8; j++) {
            float2 sc = fsincos(rotg[(size_t)srow * DH + c0 + j]);
            o0.e[j] = (short)f2bf(a[j] * sc.y - b[j] * sc.x);
            o1.e[j] = (short)f2bf(b[j] * sc.y + a[j] * sc.x);
        }
        int sw2 = (rr & 7) << 3;
        *(s16x8*)&QPs[rr * 64 + (c0 ^ sw2)]        = o0.v;
        *(s16x8*)&QPs[rr * 64 + ((c0 + 32) ^ sw2)] = o1.v;
    }
    __syncthreads();

    s16x8 qf[2];
#pragma unroll
    for (int ks = 0; ks < 2; ks++)
        qf[ks] = *(const s16x8*)&QPs[(wv * 16 + l15) * 64 + ((ks * 32 + quad * 8) ^ swl)];

    F4 oa[4];
#pragma unroll
    for (int mb = 0; mb < 4; mb++) oa[mb].v = (f32x4){0.f, 0.f, 0.f, 0.f};
    float lsum = 0.f;

    for (int kt = 0; kt < nkt; kt++) {
        const int cb = kt & 1;
        {
            int rr = tid >> 2, c0 = (tid & 3) * 8;
            int srow = kt * BN + rr;
            const float* gk = kg + kvbase + (size_t)srow * DH;
            float a[8], b[8];
            *(float4*)&a[0] = *(const float4*)(gk + c0);
            *(float4*)&a[4] = *(const float4*)(gk + c0 + 4);
            *(float4*)&b[0] = *(const float4*)(gk + c0 + 32);
            *(float4*)&b[4] = *(const float4*)(gk + c0 + 36);
            U8 o0, o1;
#pragma unroll
            for (int j = 0; j < 8; j++) {
                float2 sc = fsincos(rotg[(size_t)(srow & (SQ - 1)) * DH + c0 + j]);
                o0.e[j] = (short)f2bf(a[j] * sc.y - b[j] * sc.x);
                o1.e[j] = (short)f2bf(b[j] * sc.y + a[j] * sc.x);
            }
            int sw2 = (rr & 7) << 3;
            *(s16x8*)&Ks[cb][rr * 64 + (c0 ^ sw2)]        = o0.v;
            *(s16x8*)&Ks[cb][rr * 64 + ((c0 + 32) ^ sw2)] = o1.v;
        }
        {
            int rr = tid >> 2, c0 = (tid & 3) * 16;
            const float* gv = vg + kvbase + (size_t)(kt * BN + rr) * DH;
            float vv[16];
#pragma unroll
            for (int t = 0; t < 4; t++)
                *(float4*)&vv[t * 4] = *(const float4*)(gv + c0 + t * 4);
#pragma unroll
            for (int j = 0; j < 16; j++) {
                int d = c0 + j;
                Vt[cb][d * 64 + (rr ^ ((d & 7) << 3))] = (short)f2bf(vv[j]);
            }
        }
        __syncthreads();

        F4 sa[4];
#pragma unroll
        for (int mb = 0; mb < 4; mb++) sa[mb].v = (f32x4){0.f, 0.f, 0.f, 0.f};
#pragma unroll
        for (int ks = 0; ks < 2; ks++)
#pragma unroll
            for (int mb = 0; mb < 4; mb++) {
                s16x8 kf = *(const s16x8*)&Ks[cb][(mb * 16 + l15) * 64 + ((ks * 32 + quad * 8) ^ swl)];
                sa[mb].v = __builtin_amdgcn_mfma_f32_16x16x32_bf16(kf, qf[ks], sa[mb].v, 0, 0, 0);
            }

        F4 pa[4];
#pragma unroll
        for (int mb = 0; mb < 4; mb++)
#pragma unroll
            for (int c = 0; c < 4; c++) {
                float t  = sa[mb].e[c] * K1F;
                float w2 = t * t;
                float poly = fmaf(w2, fmaf(w2, KPAF, KPBF), 1.0f);
                pa[mb].e[c] = exp2hw(fmaf(t, poly, -KEF));
            }
        if (kt == 31 && qglob < SPECIAL_START) {
#pragma unroll
            for (int mb = 0; mb < 4; mb++)
#pragma unroll
                for (int c = 0; c < 4; c++) {
                    int kvglob = kt * BN + mb * 16 + quad * 4 + c;
                    if (kvglob >= SPECIAL_START) pa[mb].e[c] = 0.f;
                }
        }
        short* prow = &QPs[(wv * 16 + l15) * 64];
#pragma unroll
        for (int mb = 0; mb < 4; mb++) {
            lsum += (pa[mb].e[0] + pa[mb].e[1]) + (pa[mb].e[2] + pa[mb].e[3]);
            uint2 pw = make_uint2(pkbf(pa[mb].e[0], pa[mb].e[1]),
                                  pkbf(pa[mb].e[2], pa[mb].e[3]));
            *(uint2*)&prow[(mb * 16 + quad * 4) ^ swl] = pw;
        }
#pragma unroll
        for (int ks = 0; ks < 2; ks++) {
            s16x8 pf = *(const s16x8*)&prow[(ks * 32 + quad * 8) ^ swl];
#pragma unroll
            for (int mb = 0; mb < 4; mb++) {
                s16x8 vf = *(const s16x8*)&Vt[cb][(mb * 16 + l15) * 64 + ((ks * 32 + quad * 8) ^ swl)];
                oa[mb].v = __builtin_amdgcn_mfma_f32_16x16x32_bf16(vf, pf, oa[mb].v, 0, 0, 0);
            }
        }
        __syncthreads();
    }

    lsum += __shfl_xor(lsum, 16, 64);
    lsum += __shfl_xor(lsum, 32, 64);

    float rl = 1.0f / lsum;
    int qrow = qs + wv * 16 + l15;
    float* orow = outg + ((size_t)bh * SQ + qrow) * DH;
#pragma unroll
    for (int mb = 0; mb < 4; mb++) {
        int d0 = mb * 16 + quad * 4;
        *(float4*)(orow + d0) = make_float4(oa[mb].e[0] * rl, oa[mb].e[1] * rl,
                                            oa[mb].e[2] * rl, oa[mb].e[3] * rl);
    }
}

extern "C" void kernel_launch(void* const* d_in, const int* in_sizes, int n_in,
                              void* d_out, int out_size, void* d_ws, size_t ws_size,
                              hipStream_t stream) {
    const float* q   = (const float*)d_in[0];
    const float* k   = (const float*)d_in[1];
    const float* v   = (const float*)d_in[2];
    const float* rot = (const float*)d_in[3];
    float* out = (float*)d_out;

    char* w = (char*)d_ws;
    const size_t k_bytes = (size_t)NKV * SQ * DH * sizeof(u16);     // 2 MiB
    const size_t v_bytes = k_bytes;                                 // 2 MiB
    size_t off = k_bytes + v_bytes;
    uint32_t* cnt = (uint32_t*)(w + off); off += 256;
    float* pacc = (float*)(w + off); off += (size_t)NITEMS_F * 8192 * sizeof(float);
    float* lacc = (float*)(w + off); off += (size_t)NITEMS_F * 128 * sizeof(float);
    const size_t full_need = off;                                   // ~47 MB

    u16* kp = (u16*)w;
    u16* vp = (u16*)(w + k_bytes);

    if (ws_size >= full_need) {
        hipLaunchKernelGGL(prep_kernel, dim3(VTILES + KBLK), dim3(256), 0, stream,
                           k, v, rot, kp, vp, cnt);
        hipLaunchKernelGGL(attn_fast, dim3(ATTN_GRID_F), dim3(256), 0, stream,
                           q, rot, kp, vp, cnt, pacc, lacc, out);
        hipLaunchKernelGGL(reduce_kernel, dim3(RED_GRID), dim3(256), 0, stream,
                           pacc, lacc, out);
    } else {
        hipLaunchKernelGGL(attn_fallback, dim3(32, NBH), dim3(256), 0, stream,
                           q, k, v, rot, out);
    }
}

// Round 13
// 126.092 us; speedup vs baseline: 2.6900x; 1.0433x over previous
//
#include <hip/hip_runtime.h>
#include <stdint.h>

typedef unsigned short u16;
typedef short s16x8 __attribute__((ext_vector_type(8)));
typedef float f32x4 __attribute__((ext_vector_type(4)));

#define SQ 2048
#define DH 64
#define BN 64
#define STR 72             // prep-only LDS transpose stride (shorts)
#define SPECIAL_START 2040
#define NBH 32             // b*h
#define NKV 8              // b*hk
#define NQP 16             // qp (128-row) index 0..15
#define NCLS 40            // slice classes per bh (<=8 ktiles each)
#define NITEMS_F (NCLS * 32)   // 1280 sliced items
#define ATTN_GRID_F 768        // 3 blocks/CU
// softclamp+softmax folded to exp2: p = 2^( t*poly(t*t) - KEF ), t = s * K1F
#define K1F  0.18033688011112043f    // 0.125 * log2(e)
#define KPAF 4.9244826e-9f           // (2/15)*k^2, k = (0.02/log2e)^2
#define KPBF -6.406040185576019e-5f  // -k/3
#define KEF  36.067376022224085f     // 25 * log2(e)  (constant softmax shift = 25)

union U8 { s16x8 v; short e[8]; };
union F4 { f32x4 v; float e[4]; };

// class: qp | kt0<<4 | nk<<9 | nsl<<13  (heavy-first; measured R7/R10 = 55us attn)
#define CL(qp,k0,nk,ns) ((unsigned short)((qp) | ((k0) << 4) | ((nk) << 9) | ((ns) << 13)))
__device__ const unsigned short ETAB[NCLS] = {
    CL(15,0,8,4), CL(15,8,8,4), CL(15,16,8,4), CL(15,24,8,4),
    CL(14,0,8,4), CL(14,8,8,4), CL(14,16,8,4), CL(14,24,8,4),
    CL(13,0,8,4), CL(13,8,8,4), CL(13,16,8,4),
    CL(12,0,8,4), CL(12,8,8,4), CL(12,16,8,4),
    CL(11,0,8,3), CL(11,8,8,3), CL(11,16,8,3),
    CL(10,0,8,3), CL(10,8,8,3), CL(10,16,8,3),
    CL(9,0,8,3),  CL(9,8,8,3),
    CL(8,0,8,3),  CL(8,8,8,3),
    CL(7,0,8,2),  CL(7,8,8,2),
    CL(6,0,8,2),  CL(6,8,8,2),
    CL(5,0,8,2),
    CL(4,0,8,2),
    CL(3,0,8,1),
    CL(2,0,8,1),
    CL(13,24,4,4), CL(12,24,4,4), CL(9,16,4,3), CL(8,16,4,3),
    CL(5,8,4,2),   CL(4,8,4,2),   CL(1,0,4,1),  CL(0,0,4,1)
};
// per-qp class-id lists (pad -1) — consumed by the fused last-finisher combine
__device__ const signed char QPS[16][4] = {
    {39,-1,-1,-1}, {38,-1,-1,-1}, {31,-1,-1,-1}, {30,-1,-1,-1},
    {29,37,-1,-1}, {28,36,-1,-1}, {26,27,-1,-1}, {24,25,-1,-1},
    {22,23,35,-1}, {20,21,34,-1}, {17,18,19,-1}, {14,15,16,-1},
    {11,12,13,33}, {8,9,10,32},   {4,5,6,7},     {0,1,2,3}
};

__device__ __forceinline__ u16 f2bf(float x) {  // round-to-nearest-even
    uint32_t u = __float_as_uint(x);
    return (u16)((u + 0x7fffu + ((u >> 16) & 1u)) >> 16);
}
__device__ __forceinline__ uint32_t pkbf(float a, float b) {  // pack 2 bf16, 1 instr
    uint32_t r;
    asm("v_cvt_pk_bf16_f32 %0, %1, %2" : "=v"(r) : "v"(a), "v"(b));
    return r;
}
__device__ __forceinline__ float exp2hw(float x) {
    float r; asm("v_exp_f32 %0, %1" : "=v"(r) : "v"(x)); return r;
}
__device__ __forceinline__ float2 fsincos(float ang) {  // {sin, cos}, fast HW path
    float r = ang * 0.15915494309189535f;   // radians -> revolutions
    r -= floorf(r);
    float s, c;
    asm("v_sin_f32 %0, %1" : "=v"(s) : "v"(r));
    asm("v_cos_f32 %0, %1" : "=v"(c) : "v"(r));
    return make_float2(s, c);
}
// async global->LDS, 16B per lane; LDS dest = wave-uniform base + lane*16
__device__ __forceinline__ void gl_lds16(const void* g, void* l) {
    __builtin_amdgcn_global_load_lds(
        (const __attribute__((address_space(1))) uint32_t*)g,
        (__attribute__((address_space(3))) uint32_t*)l, 16, 0, 0);
}
// ---- device-coherent (cross-XCD) accesses: sc0 sc1 bypass the per-XCD L2.
// NO L2 flushes (R9 lesson: __threadfence = L2 writeback poison).
// asm operands: ext_vector (f32x4) / scalar only (R11 lesson: float4 struct
// does not bind to 'v').
__device__ __forceinline__ void st_f4_dev(float* p, f32x4 v) {
    asm volatile("global_store_dwordx4 %0, %1, off sc0 sc1"
                 :: "v"((uint64_t)(uintptr_t)p), "v"(v) : "memory");
}
__device__ __forceinline__ void st_f1_dev(float* p, float v) {
    asm volatile("global_store_dword %0, %1, off sc0 sc1"
                 :: "v"((uint64_t)(uintptr_t)p), "v"(v) : "memory");
}
// batched coherent load of the 4 mb-fragments of one row: they sit at
// +0/+64/+128/+192 BYTES (mb*16 floats) — R12's 256B stride was the bug.
// waitcnt inside the asm block => outputs valid on exit (rule-18 safe).
__device__ __forceinline__ void ld4_f4_dev(const float* p, f32x4& a, f32x4& b,
                                           f32x4& c, f32x4& d) {
    asm volatile(
        "global_load_dwordx4 %0, %4, off sc0 sc1\n\t"
        "global_load_dwordx4 %1, %4, off offset:64 sc0 sc1\n\t"
        "global_load_dwordx4 %2, %4, off offset:128 sc0 sc1\n\t"
        "global_load_dwordx4 %3, %4, off offset:192 sc0 sc1\n\t"
        "s_waitcnt vmcnt(0)"
        : "=&v"(a), "=&v"(b), "=&v"(c), "=&v"(d)
        : "v"((uint64_t)(uintptr_t)p) : "memory");
}
__device__ __forceinline__ float ld_f1_dev(const float* p) {
    float r;
    asm volatile("global_load_dword %0, %1, off sc0 sc1\n\ts_waitcnt vmcnt(0)"
                 : "=&v"(r) : "v"((uint64_t)(uintptr_t)p) : "memory");
    return r;
}

// ---- prep: V tiles (transpose to [tile][d][kv]) + K rope rows (bf16) ----
#define VTILES (NKV * 32)                 // 256 tile-blocks
#define RK (NKV * SQ)                     // 16384 K rows
#define KBLK (RK / 32)                    // 512 row-blocks
__global__ __launch_bounds__(256)
void prep_kernel(const float* __restrict__ kg, const float* __restrict__ vg,
                 const float* __restrict__ rotg,
                 u16* __restrict__ kp, u16* __restrict__ vp,
                 uint32_t* __restrict__ cnt, uint32_t* __restrict__ done)
{
    const int tid = threadIdx.x;
    if (blockIdx.x == 0) {                 // reset queue + combine counters
        if (tid == 0) *cnt = 0u;
        done[tid] = 0u;
        done[tid + 256] = 0u;
    }
    if (blockIdx.x < VTILES) {
        __shared__ short Vls[64 * STR];
        const int tile = blockIdx.x;                   // bkv*32 + kt
        const float* src = vg + ((size_t)(tile >> 5) * SQ + (size_t)(tile & 31) * 64) * DH;
        {
            int kv = tid >> 2, c0 = (tid & 3) * 16;
            const float* s4 = src + (size_t)kv * DH + c0;
            float4 f0 = *(const float4*)(s4);
            float4 f1 = *(const float4*)(s4 + 4);
            float4 f2 = *(const float4*)(s4 + 8);
            float4 f3 = *(const float4*)(s4 + 12);
            uint4 w0 = make_uint4(pkbf(f0.x, f0.y), pkbf(f0.z, f0.w),
                                  pkbf(f1.x, f1.y), pkbf(f1.z, f1.w));
            uint4 w1 = make_uint4(pkbf(f2.x, f2.y), pkbf(f2.z, f2.w),
                                  pkbf(f3.x, f3.y), pkbf(f3.z, f3.w));
            *(uint4*)&Vls[kv * STR + c0]     = w0;
            *(uint4*)&Vls[kv * STR + c0 + 8] = w1;
        }
        __syncthreads();
        {
            int d = tid >> 2, c0 = (tid & 3) * 16;
            U8 o0, o1;
#pragma unroll
            for (int j = 0; j < 16; j++)
                (j < 8 ? o0 : o1).e[j & 7] = Vls[(c0 + j) * STR + d];  // transpose
            u16* dst = vp + (((size_t)tile * 64 + d) << 6) + c0;
            *(s16x8*)dst       = o0.v;
            *(s16x8*)(dst + 8) = o1.v;
        }
    } else {
        int bx = blockIdx.x - VTILES;
        int r8 = tid >> 3, c0 = (tid & 7) * 4;      // c0 in 0..28 (<32)
        int r = bx * 32 + r8;                        // r in [0, RK)
        const int s = r & (SQ - 1);
        const float* src = kg + (size_t)r * DH;
        u16*         dst = kp + (size_t)r * DH;
        float4 a  = *(const float4*)(src + c0);
        float4 b  = *(const float4*)(src + c0 + 32);
        float4 rv = *(const float4*)(rotg + (size_t)s * DH + c0);
        float2 s0 = fsincos(rv.x), s1 = fsincos(rv.y),
               s2 = fsincos(rv.z), s3 = fsincos(rv.w);
        float lo0 = a.x * s0.y - b.x * s0.x, hi0 = b.x * s0.y + a.x * s0.x;
        float lo1 = a.y * s1.y - b.y * s1.x, hi1 = b.y * s1.y + a.y * s1.x;
        float lo2 = a.z * s2.y - b.z * s2.x, hi2 = b.z * s2.y + a.z * s2.x;
        float lo3 = a.w * s3.y - b.w * s3.x, hi3 = b.w * s3.y + a.w * s3.x;
        *(uint2*)(dst + c0)      = make_uint2(pkbf(lo0, lo1), pkbf(lo2, lo3));
        *(uint2*)(dst + c0 + 32) = make_uint2(pkbf(hi0, hi1), pkbf(hi2, hi3));
    }
}

// ---- attn: R10 body (measured 55us) + fused last-finisher combine via
// device-coherent sc0sc1 stores/loads (fence-free; no reduce kernel).
__global__ __launch_bounds__(256)
__attribute__((amdgpu_waves_per_eu(3, 4)))
void attn_fast(const float* __restrict__ qg, const float* __restrict__ rotg,
               const u16* __restrict__ kp, const u16* __restrict__ vp,
               uint32_t* __restrict__ cnt, uint32_t* __restrict__ done,
               float* __restrict__ pacc, float* __restrict__ lacc,
               float* __restrict__ outg)
{
    const int tid = threadIdx.x;
    const int wv = tid >> 6, lane = tid & 63;
    const int l15 = lane & 15, quad = lane >> 4;
    const int swl = (l15 & 7) << 3;            // fragment-row swizzle (shorts)

    __shared__ __align__(16) u16 Ks[2][4096];  // 16 KB K dbuf
    __shared__ __align__(16) u16 Vt[2][4096];  // 16 KB V dbuf
    __shared__ __align__(16) short Ps[128 * 64]; // 16 KB wave-private P
    __shared__ int s_w, s_d;

    // staging geometry (rule 21): linear LDS dest + inverse-swizzled source
    const int gcol = (((lane & 7) ^ (lane >> 3)) << 3);
    const int goff0 = ((wv * 16 + (lane >> 3)) << 6) + gcol;
    const int goff1 = goff0 + (8 << 6);
    const int lds0 = (wv * 2) * 512;           // wave-uniform
    const int lds1 = lds0 + 512;

    short* prow0 = &Ps[(wv * 32 + l15) * 64];
    short* prow1 = &Ps[(wv * 32 + 16 + l15) * 64];

    for (;;) {
        __syncthreads();                       // protect s_w/s_d + LDS reuse
        if (tid == 0) s_w = (int)atomicAdd(cnt, 1u);
        __syncthreads();
        const int w = s_w;
        if (w >= NITEMS_F) break;
        const int g = w >> 5;                  // class (heavy-first)
        const int u = w & 31, bkv = u >> 2;    // consecutive pops share bkv
        const int bh = ((bkv >> 2) << 4) | ((bkv & 3) << 2) | (u & 3);
        const int e = ETAB[g];
        const int qp  = e & 15;
        const int kt0 = (e >> 4) & 31;
        const int nk  = (e >> 9) & 15;         // 4 or 8
        const int nsl = e >> 13;               // slices for this qp
        const int qrow0 = qp * 128 + wv * 32;

        const u16* kbase = kp + (size_t)bkv * (SQ * DH);
        const u16* vbase = vp + (size_t)bkv * (SQ * DH);
        auto stage = [&](int kt, int cb) {
            const u16* tk = kbase + ((size_t)kt << 12);
            const u16* tv = vbase + ((size_t)kt << 12);
            gl_lds16(tk + goff0, &Ks[cb][lds0]);
            gl_lds16(tk + goff1, &Ks[cb][lds1]);
            gl_lds16(tv + goff0, &Vt[cb][lds0]);
            gl_lds16(tv + goff1, &Vt[cb][lds1]);
        };
        stage(kt0, 0);   // first-tile DMA flies under the Q rope below

        // ---- Q rope -> registers ----
        s16x8 qf[2][2];
#pragma unroll
        for (int nq = 0; nq < 2; nq++) {
            const int srow = qrow0 + nq * 16 + l15;
            const float* gq = qg + ((size_t)bh * SQ + srow) * DH + quad * 8;
            float a[8], b[8];
            *(float4*)&a[0] = *(const float4*)(gq);
            *(float4*)&a[4] = *(const float4*)(gq + 4);
            *(float4*)&b[0] = *(const float4*)(gq + 32);
            *(float4*)&b[4] = *(const float4*)(gq + 36);
            const float* rrow = rotg + (size_t)srow * DH + quad * 8;
            float lo[8], hi[8];
#pragma unroll
            for (int j = 0; j < 8; j++) {
                float2 sc = fsincos(rrow[j]);
                lo[j] = a[j] * sc.y - b[j] * sc.x;
                hi[j] = b[j] * sc.y + a[j] * sc.x;
            }
            U8 q0, q1;
#pragma unroll
            for (int j = 0; j < 4; j++) {
                ((uint32_t*)&q0.v)[j] = pkbf(lo[2 * j], lo[2 * j + 1]);
                ((uint32_t*)&q1.v)[j] = pkbf(hi[2 * j], hi[2 * j + 1]);
            }
            qf[nq][0] = q0.v;
            qf[nq][1] = q1.v;
        }

        F4 oa[2][4];
#pragma unroll
        for (int nq = 0; nq < 2; nq++)
#pragma unroll
            for (int mb = 0; mb < 4; mb++) oa[nq][mb].v = (f32x4){0.f, 0.f, 0.f, 0.f};
        F4 lsa0, lsa1;
        lsa0.v = (f32x4){0.f, 0.f, 0.f, 0.f};
        lsa1.v = (f32x4){0.f, 0.f, 0.f, 0.f};

        __syncthreads();   // first tile staged (drains vmcnt)
        int cb = 0;

        for (int i = 0; i < nk; i++) {
            const int kt = kt0 + i;
            if (i + 1 < nk) stage(kt + 1, cb ^ 1);  // full phase before drain

            // ---- QK^T: S^T[kv][q]; each kf feeds both q-tiles ----
            F4 sa[2][4];
            __builtin_amdgcn_s_setprio(1);
#pragma unroll
            for (int ks = 0; ks < 2; ks++)
#pragma unroll
                for (int mb = 0; mb < 4; mb++) {
                    s16x8 kf = *(const s16x8*)&Ks[cb][(mb * 16 + l15) * 64 + ((ks * 32 + quad * 8) ^ swl)];
                    sa[0][mb].v = __builtin_amdgcn_mfma_f32_16x16x32_bf16(
                        kf, qf[0][ks], ks ? sa[0][mb].v : (f32x4){0.f, 0.f, 0.f, 0.f}, 0, 0, 0);
                    sa[1][mb].v = __builtin_amdgcn_mfma_f32_16x16x32_bf16(
                        kf, qf[1][ks], ks ? sa[1][mb].v : (f32x4){0.f, 0.f, 0.f, 0.f}, 0, 0, 0);
                }
            __builtin_amdgcn_s_setprio(0);

            // ---- softclamp + constant-shift softmax (exp2-folded, vectorized) ----
            const int last = (kt == 31);
#pragma unroll
            for (int nq = 0; nq < 2; nq++) {
                const int qglob = qrow0 + nq * 16 + l15;
                short* prow = nq ? prow1 : prow0;
#pragma unroll
                for (int mb = 0; mb < 4; mb++) {
                    F4 t, w2, py, pa;
                    t.v  = sa[nq][mb].v * K1F;
                    w2.v = t.v * t.v;
                    py.v = w2.v * KPAF + KPBF;
                    py.v = w2.v * py.v + 1.0f;
                    t.v  = t.v * py.v - KEF;
                    pa.e[0] = exp2hw(t.e[0]);
                    pa.e[1] = exp2hw(t.e[1]);
                    pa.e[2] = exp2hw(t.e[2]);
                    pa.e[3] = exp2hw(t.e[3]);
                    if (last && qglob < SPECIAL_START) {   // special-token mask
#pragma unroll
                        for (int c = 0; c < 4; c++) {
                            int kvglob = kt * BN + mb * 16 + quad * 4 + c;
                            if (kvglob >= SPECIAL_START) pa.e[c] = 0.f;
                        }
                    }
                    if (nq) lsa1.v = lsa1.v + pa.v; else lsa0.v = lsa0.v + pa.v;
                    uint2 pw = make_uint2(pkbf(pa.e[0], pa.e[1]),
                                          pkbf(pa.e[2], pa.e[3]));
                    *(uint2*)&prow[(mb * 16 + quad * 4) ^ swl] = pw;  // wave-private
                }
            }

            // ---- PV: O^T[d][q] += Vt.P; each vf feeds both q-tiles ----
            s16x8 pf00 = *(const s16x8*)&prow0[(quad * 8) ^ swl];
            s16x8 pf01 = *(const s16x8*)&prow0[(32 + quad * 8) ^ swl];
            s16x8 pf10 = *(const s16x8*)&prow1[(quad * 8) ^ swl];
            s16x8 pf11 = *(const s16x8*)&prow1[(32 + quad * 8) ^ swl];
            __builtin_amdgcn_s_setprio(1);
#pragma unroll
            for (int mb = 0; mb < 4; mb++) {
                s16x8 vf = *(const s16x8*)&Vt[cb][(mb * 16 + l15) * 64 + ((quad * 8) ^ swl)];
                oa[0][mb].v = __builtin_amdgcn_mfma_f32_16x16x32_bf16(vf, pf00, oa[0][mb].v, 0, 0, 0);
                oa[1][mb].v = __builtin_amdgcn_mfma_f32_16x16x32_bf16(vf, pf10, oa[1][mb].v, 0, 0, 0);
            }
#pragma unroll
            for (int mb = 0; mb < 4; mb++) {
                s16x8 vf = *(const s16x8*)&Vt[cb][(mb * 16 + l15) * 64 + ((32 + quad * 8) ^ swl)];
                oa[0][mb].v = __builtin_amdgcn_mfma_f32_16x16x32_bf16(vf, pf01, oa[0][mb].v, 0, 0, 0);
                oa[1][mb].v = __builtin_amdgcn_mfma_f32_16x16x32_bf16(vf, pf11, oa[1][mb].v, 0, 0, 0);
            }
            __builtin_amdgcn_s_setprio(0);

            __syncthreads();   // buf[cb] reads done; kt+1 DMA landed
            cb ^= 1;
        }

        // ---- row lsums across quads (kv partitioned by quad) ----
        float lsum0 = (lsa0.e[0] + lsa0.e[1]) + (lsa0.e[2] + lsa0.e[3]);
        float lsum1 = (lsa1.e[0] + lsa1.e[1]) + (lsa1.e[2] + lsa1.e[3]);
        lsum0 += __shfl_xor(lsum0, 16, 64);
        lsum0 += __shfl_xor(lsum0, 32, 64);
        lsum1 += __shfl_xor(lsum1, 16, 64);
        lsum1 += __shfl_xor(lsum1, 32, 64);

        if (nsl == 1) {
            // ---- single-slice qp: direct write (plain stores) ----
#pragma unroll
            for (int nq = 0; nq < 2; nq++) {
                const float rl = 1.0f / (nq ? lsum1 : lsum0);
                const int qrow = qrow0 + nq * 16 + l15;
                float* orow = outg + ((size_t)bh * SQ + qrow) * DH;
#pragma unroll
                for (int mb = 0; mb < 4; mb++) {
                    const int d0 = mb * 16 + quad * 4;
                    const F4& o = oa[nq][mb];
                    *(float4*)(orow + d0) = make_float4(o.e[0] * rl, o.e[1] * rl,
                                                        o.e[2] * rl, o.e[3] * rl);
                }
            }
        } else {
            // ---- coherent-store partials; last finisher combines (fence-free) ----
            float* pitem = pacc + (size_t)w * 8192;
            float* litem = lacc + (size_t)w * 128;
#pragma unroll
            for (int nq = 0; nq < 2; nq++) {
                const int row = wv * 32 + nq * 16 + l15;
#pragma unroll
                for (int mb = 0; mb < 4; mb++)
                    st_f4_dev(&pitem[row * 64 + mb * 16 + quad * 4], oa[nq][mb].v);
                if (quad == 0) st_f1_dev(&litem[row], nq ? lsum1 : lsum0);
            }
            asm volatile("s_waitcnt vmcnt(0)" ::: "memory");  // stores at coherent pt
            __syncthreads();
            if (tid == 0) s_d = (int)atomicAdd(&done[bh * 16 + qp], 1u);
            __syncthreads();
            if (s_d == nsl - 1) {          // we are the last slice: combine
#pragma unroll
                for (int s = 0; s < 4; s++) {
                    const int g2 = QPS[qp][s];
                    if (g2 < 0 || g2 == g) continue;
                    const size_t id = (size_t)g2 * 32 + u;
                    const float* pp = pacc + id * 8192;
                    const float* lp = lacc + id * 128;
#pragma unroll
                    for (int nq = 0; nq < 2; nq++) {
                        const int row = wv * 32 + nq * 16 + l15;
                        f32x4 v0, v1, v2, v3;
                        ld4_f4_dev(&pp[row * 64 + quad * 4], v0, v1, v2, v3);
                        oa[nq][0].v = oa[nq][0].v + v0;
                        oa[nq][1].v = oa[nq][1].v + v1;
                        oa[nq][2].v = oa[nq][2].v + v2;
                        oa[nq][3].v = oa[nq][3].v + v3;
                        const float lsb = ld_f1_dev(&lp[row]);
                        if (nq) lsum1 += lsb; else lsum0 += lsb;
                    }
                }
#pragma unroll
                for (int nq = 0; nq < 2; nq++) {
                    const float rl = 1.0f / (nq ? lsum1 : lsum0);
                    const int qrow = qrow0 + nq * 16 + l15;
                    float* orow = outg + ((size_t)bh * SQ + qrow) * DH;
#pragma unroll
                    for (int mb = 0; mb < 4; mb++) {
                        const int d0 = mb * 16 + quad * 4;
                        const F4& o = oa[nq][mb];
                        *(float4*)(orow + d0) = make_float4(o.e[0] * rl, o.e[1] * rl,
                                                            o.e[2] * rl, o.e[3] * rl);
                    }
                }
            }
        }
    }
}

// ---- fallback (no workspace): self-contained, K/V staged through LDS ----
__global__ __launch_bounds__(256, 4)
void attn_fallback(const float* __restrict__ qg, const float* __restrict__ kg,
                   const float* __restrict__ vg, const float* __restrict__ rotg,
                   float* __restrict__ outg)
{
    const int x  = blockIdx.x;
    const int qt = (x & 1) ? (31 - (x >> 1)) : (x >> 1);
    const int bh = blockIdx.y;
    const int bb = bh >> 4, hh = bh & 15;
    const int bkv = bb * 4 + (hh >> 2);
    const int qs = qt * 64;

    const int tid = threadIdx.x;
    const int wv = tid >> 6, lane = tid & 63;
    const int l15 = lane & 15, quad = lane >> 4;
    const int swl = (l15 & 7) << 3;

    __shared__ __align__(16) short QPs[64 * 64];
    __shared__ __align__(16) short Ks[2][BN * 64];
    __shared__ __align__(16) short Vt[2][DH * 64];

    const size_t kvbase = ((size_t)bkv * SQ) * DH;
    const int nkt = (qt / 4 + 1) * 4;
    const int qglob = qs + wv * 16 + l15;

    {
        int rr = tid >> 2, c0 = (tid & 3) * 8;
        int srow = qs + rr;
        const float* gq = qg + ((size_t)bh * SQ + srow) * DH;
        float a[8], b[8];
        *(float4*)&a[0] = *(const float4*)(gq + c0);
        *(float4*)&a[4] = *(const float4*)(gq + c0 + 4);
        *(float4*)&b[0] = *(const float4*)(gq + c0 + 32);
        *(float4*)&b[4] = *(const float4*)(gq + c0 + 36);
        U8 o0, o1;
#pragma unroll
        for (int j = 0; j < 8; j++) {
            float2 sc = fsincos(rotg[(size_t)srow * DH + c0 + j]);
            o0.e[j] = (short)f2bf(a[j] * sc.y - b[j] * sc.x);
            o1.e[j] = (short)f2bf(b[j] * sc.y + a[j] * sc.x);
        }
        int sw2 = (rr & 7) << 3;
        *(s16x8*)&QPs[rr * 64 + (c0 ^ sw2)]        = o0.v;
        *(s16x8*)&QPs[rr * 64 + ((c0 + 32) ^ sw2)] = o1.v;
    }
    __syncthreads();

    s16x8 qf[2];
#pragma unroll
    for (int ks = 0; ks < 2; ks++)
        qf[ks] = *(const s16x8*)&QPs[(wv * 16 + l15) * 64 + ((ks * 32 + quad * 8) ^ swl)];

    F4 oa[4];
#pragma unroll
    for (int mb = 0; mb < 4; mb++) oa[mb].v = (f32x4){0.f, 0.f, 0.f, 0.f};
    float lsum = 0.f;

    for (int kt = 0; kt < nkt; kt++) {
        const int cb = kt & 1;
        {
            int rr = tid >> 2, c0 = (tid & 3) * 8;
            int srow = kt * BN + rr;
            const float* gk = kg + kvbase + (size_t)srow * DH;
            float a[8], b[8];
            *(float4*)&a[0] = *(const float4*)(gk + c0);
            *(float4*)&a[4] = *(const float4*)(gk + c0 + 4);
            *(float4*)&b[0] = *(const float4*)(gk + c0 + 32);
            *(float4*)&b[4] = *(const float4*)(gk + c0 + 36);
            U8 o0, o1;
#pragma unroll
            for (int j = 0; j < 8; j++) {
                float2 sc = fsincos(rotg[(size_t)(srow & (SQ - 1)) * DH + c0 + j]);
                o0.e[j] = (short)f2bf(a[j] * sc.y - b[j] * sc.x);
                o1.e[j] = (short)f2bf(b[j] * sc.y + a[j] * sc.x);
            }
            int sw2 = (rr & 7) << 3;
            *(s16x8*)&Ks[cb][rr * 64 + (c0 ^ sw2)]        = o0.v;
            *(s16x8*)&Ks[cb][rr * 64 + ((c0 + 32) ^ sw2)] = o1.v;
        }
        {
            int rr = tid >> 2, c0 = (tid & 3) * 16;
            const float* gv = vg + kvbase + (size_t)(kt * BN + rr) * DH;
            float vv[16];
#pragma unroll
            for (int t = 0; t < 4; t++)
                *(float4*)&vv[t * 4] = *(const float4*)(gv + c0 + t * 4);
#pragma unroll
            for (int j = 0; j < 16; j++) {
                int d = c0 + j;
                Vt[cb][d * 64 + (rr ^ ((d & 7) << 3))] = (short)f2bf(vv[j]);
            }
        }
        __syncthreads();

        F4 sa[4];
#pragma unroll
        for (int mb = 0; mb < 4; mb++) sa[mb].v = (f32x4){0.f, 0.f, 0.f, 0.f};
#pragma unroll
        for (int ks = 0; ks < 2; ks++)
#pragma unroll
            for (int mb = 0; mb < 4; mb++) {
                s16x8 kf = *(const s16x8*)&Ks[cb][(mb * 16 + l15) * 64 + ((ks * 32 + quad * 8) ^ swl)];
                sa[mb].v = __builtin_amdgcn_mfma_f32_16x16x32_bf16(kf, qf[ks], sa[mb].v, 0, 0, 0);
            }

        F4 pa[4];
#pragma unroll
        for (int mb = 0; mb < 4; mb++)
#pragma unroll
            for (int c = 0; c < 4; c++) {
                float t  = sa[mb].e[c] * K1F;
                float w2 = t * t;
                float poly = fmaf(w2, fmaf(w2, KPAF, KPBF), 1.0f);
                pa[mb].e[c] = exp2hw(fmaf(t, poly, -KEF));
            }
        if (kt == 31 && qglob < SPECIAL_START) {
#pragma unroll
            for (int mb = 0; mb < 4; mb++)
#pragma unroll
                for (int c = 0; c < 4; c++) {
                    int kvglob = kt * BN + mb * 16 + quad * 4 + c;
                    if (kvglob >= SPECIAL_START) pa[mb].e[c] = 0.f;
                }
        }
        short* prow = &QPs[(wv * 16 + l15) * 64];
#pragma unroll
        for (int mb = 0; mb < 4; mb++) {
            lsum += (pa[mb].e[0] + pa[mb].e[1]) + (pa[mb].e[2] + pa[mb].e[3]);
            uint2 pw = make_uint2(pkbf(pa[mb].e[0], pa[mb].e[1]),
                                  pkbf(pa[mb].e[2], pa[mb].e[3]));
            *(uint2*)&prow[(mb * 16 + quad * 4) ^ swl] = pw;
        }
#pragma unroll
        for (int ks = 0; ks < 2; ks++) {
            s16x8 pf = *(const s16x8*)&prow[(ks * 32 + quad * 8) ^ swl];
#pragma unroll
            for (int mb = 0; mb < 4; mb++) {
                s16x8 vf = *(const s16x8*)&Vt[cb][(mb * 16 + l15) * 64 + ((ks * 32 + quad * 8) ^ swl)];
                oa[mb].v = __builtin_amdgcn_mfma_f32_16x16x32_bf16(vf, pf, oa[mb].v, 0, 0, 0);
            }
        }
        __syncthreads();
    }

    lsum += __shfl_xor(lsum, 16, 64);
    lsum += __shfl_xor(lsum, 32, 64);

    float rl = 1.0f / lsum;
    int qrow = qs + wv * 16 + l15;
    float* orow = outg + ((size_t)bh * SQ + qrow) * DH;
#pragma unroll
    for (int mb = 0; mb < 4; mb++) {
        int d0 = mb * 16 + quad * 4;
        *(float4*)(orow + d0) = make_float4(oa[mb].e[0] * rl, oa[mb].e[1] * rl,
                                            oa[mb].e[2] * rl, oa[mb].e[3] * rl);
    }
}

extern "C" void kernel_launch(void* const* d_in, const int* in_sizes, int n_in,
                              void* d_out, int out_size, void* d_ws, size_t ws_size,
                              hipStream_t stream) {
    const float* q   = (const float*)d_in[0];
    const float* k   = (const float*)d_in[1];
    const float* v   = (const float*)d_in[2];
    const float* rot = (const float*)d_in[3];
    float* out = (float*)d_out;

    char* w = (char*)d_ws;
    const size_t k_bytes = (size_t)NKV * SQ * DH * sizeof(u16);     // 2 MiB
    const size_t v_bytes = k_bytes;                                 // 2 MiB
    size_t off = k_bytes + v_bytes;
    uint32_t* cnt  = (uint32_t*)(w + off); off += 256;
    uint32_t* done = (uint32_t*)(w + off); off += 4096;             // 512 counters
    float* pacc = (float*)(w + off); off += (size_t)NITEMS_F * 8192 * sizeof(float);
    float* lacc = (float*)(w + off); off += (size_t)NITEMS_F * 128 * sizeof(float);
    const size_t full_need = off;                                   // ~47 MB

    u16* kp = (u16*)w;
    u16* vp = (u16*)(w + k_bytes);

    if (ws_size >= full_need) {
        hipLaunchKernelGGL(prep_kernel, dim3(VTILES + KBLK), dim3(256), 0, stream,
                           k, v, rot, kp, vp, cnt, done);
        hipLaunchKernelGGL(attn_fast, dim3(ATTN_GRID_F), dim3(256), 0, stream,
                           q, rot, kp, vp, cnt, done, pacc, lacc, out);
    } else {
        hipLaunchKernelGGL(attn_fallback, dim3(32, NBH), dim3(256), 0, stream,
                           q, k, v, rot, out);
    }
}